// Round 2
// baseline (401.047 us; speedup 1.0000x reference)
//
#include <hip/hip_runtime.h>
#include <stdint.h>
#include <stddef.h>

// Causal GQA prefill attention, MI355X gfx950.
// Round 2: pair-fold load balance (block = q-tiles {p, 15-p}, constant 34
// KV-steps/block, 512 blocks), KTILE=64, XOR-swizzled LDS (conflict-free,
// 64 KiB exactly), exp2-space online softmax.
//
// Orientation trick (round 0, verified): S^T = K*Q^T via mfma_16x16x32_bf16;
// its C-layout (row=key=quad*4+r, col=q=l15) equals the A-layout of
// mfma_16x16x16bf16_1k, so softmaxed P feeds PV straight from registers.

#define S_LEN   2048
#define HQ      32
#define HKV     8
#define DH      128
#define QSTRIDE (HQ*DH)
#define KSTRIDE (HKV*DH)
// (1/sqrt(128)) * log2(e): softmax done in exp2 space
#define SCALE_L2 0.12751139830213113f

typedef __bf16 bf16;
typedef short        s16x4 __attribute__((ext_vector_type(4)));
typedef short        s16x8 __attribute__((ext_vector_type(8)));
typedef float        f32x4 __attribute__((ext_vector_type(4)));
typedef unsigned int u32x4 __attribute__((ext_vector_type(4)));

#define KTILE    64
#define KELEMS   (KTILE*DH)          // 8192 bf16, K[key][d], 16B-chunk XOR swizzle
#define VELEMS   (DH*KTILE)          // 8192 bf16, V^T[d][key], 8B-unit XOR swizzle
#define BUFELEMS (KELEMS + VELEMS)   // 16384 -> 2 buffers = 65536 B LDS

__device__ __forceinline__ unsigned int pk2(float a, float b) {
  union { bf16 h[2]; unsigned int u; } x;
  x.h[0] = (bf16)a; x.h[1] = (bf16)b;    // fptrunc = RNE
  return x.u;
}

__global__ __launch_bounds__(256, 2)
void attn_fwd(const float* __restrict__ qg, const float* __restrict__ kg,
              const float* __restrict__ vg, float* __restrict__ og) {
  __shared__ bf16 smem[2*BUFELEMS];      // 65,536 B, double-buffered

  const int tid   = threadIdx.x;
  const int lane  = tid & 63;
  const int wave  = tid >> 6;            // 4 waves/block
  const int l15   = lane & 15;
  const int quad  = lane >> 4;
  const int pairp = blockIdx.x;          // 0..7
  const int h     = blockIdx.y;          // 0..31
  const int b     = blockIdx.z;          // 0..1
  const int hkv   = h >> 2;

  // staging roles
  const int kr   = tid >> 2;             // K row (key) 0..63
  const int kc   = tid & 3;              // K col group: d = kc*32..+31
  const int vj   = tid & 31;             // V key-pair: keys 2vj, 2vj+1
  const int vgrp = tid >> 5;             // V d-group: d = vgrp*16..+15

  // XOR-swizzle tables (loop-invariant -> precomputed, no per-step VALU)
  int sw_k[4], sw_qk[4], sw_pv[4];
#pragma unroll
  for (int ii = 0; ii < 4; ++ii) sw_k[ii]  = ((kc*4 + ii)  ^ (kr  & 7)) * 8;
#pragma unroll
  for (int c  = 0; c  < 4; ++c)  sw_qk[c]  = ((c*4  + quad) ^ (l15 & 7)) * 8;
#pragma unroll
  for (int kt = 0; kt < 4; ++kt) sw_pv[kt] = ((kt*4 + quad) ^ l15) * 4;
  const int vju = vj >> 1;
  const int vjl = (vj & 1) * 2;

  const float* kbase = kg + (size_t)b*S_LEN*KSTRIDE + hkv*DH;
  const float* vbase = vg + (size_t)b*S_LEN*KSTRIDE + hkv*DH;

  float4 kx[8], vx[8];                   // prefetch registers

  auto load_tile = [&](int k0) {
    const float* kp = kbase + (size_t)(k0 + kr)*KSTRIDE + kc*32;
#pragma unroll
    for (int i = 0; i < 8; ++i) kx[i] = ((const float4*)kp)[i];
    const float* vp = vbase + (size_t)(k0 + 2*vj)*KSTRIDE + vgrp*16;
#pragma unroll
    for (int i = 0; i < 4; ++i) vx[i] = ((const float4*)vp)[i];
    const float* vp1 = vp + KSTRIDE;
#pragma unroll
    for (int i = 0; i < 4; ++i) vx[4+i] = ((const float4*)vp1)[i];
  };

  auto store_tile = [&](int bi) {
    bf16* kb   = smem + bi*BUFELEMS;
    bf16* krow = kb + kr*DH;
#pragma unroll
    for (int ii = 0; ii < 4; ++ii) {     // 16B chunks, swizzled: conflict-free
      const float4 A = kx[2*ii], B = kx[2*ii+1];
      u32x4 w;
      w[0] = pk2(A.x, A.y); w[1] = pk2(A.z, A.w);
      w[2] = pk2(B.x, B.y); w[3] = pk2(B.z, B.w);
      *(u32x4*)(krow + sw_k[ii]) = w;
    }
    bf16* vb = kb + KELEMS;
    const float* f0 = (const float*)&vx[0];   // key 2vj,   16 d-values
    const float* f1 = (const float*)&vx[4];   // key 2vj+1
#pragma unroll
    for (int i = 0; i < 16; ++i) {       // V^T[d][key], 8B-unit swizzle by d&15=i
      const int d = vgrp*16 + i;
      *(unsigned int*)(vb + d*KTILE + ((vju ^ i) << 2) + vjl) = pk2(f0[i], f1[i]);
    }
  };

  f32x4 oacc[2][8];
  float m_run[2], l_run[2];
  u32x4 qf[2][4];

  load_tile(0);

  const int qbs[2] = { pairp, 15 - pairp };   // balanced pair: 34 steps total
#pragma unroll 1
  for (int item = 0; item < 2; ++item) {
    const int qblk = qbs[item];
    const int qw   = qblk*128 + wave*32;

    // Q fragments (B-operand of S^T = K*Q^T), scale*log2e folded in
#pragma unroll
    for (int nt = 0; nt < 2; ++nt) {
      const float* qp = qg + (size_t)(b*S_LEN + qw + nt*16 + l15)*QSTRIDE
                           + h*DH + quad*8;
#pragma unroll
      for (int c = 0; c < 4; ++c) {
        const float4 a4 = ((const float4*)(qp + c*32))[0];
        const float4 b4 = ((const float4*)(qp + c*32))[1];
        u32x4 w;
        w[0] = pk2(a4.x*SCALE_L2, a4.y*SCALE_L2);
        w[1] = pk2(a4.z*SCALE_L2, a4.w*SCALE_L2);
        w[2] = pk2(b4.x*SCALE_L2, b4.y*SCALE_L2);
        w[3] = pk2(b4.z*SCALE_L2, b4.w*SCALE_L2);
        qf[nt][c] = w;
      }
    }
#pragma unroll
    for (int mt = 0; mt < 2; ++mt)
#pragma unroll
      for (int nd = 0; nd < 8; ++nd)
        oacc[mt][nd] = (f32x4){0.f, 0.f, 0.f, 0.f};
    m_run[0] = m_run[1] = -3e38f;
    l_run[0] = l_run[1] = 0.f;

    const int nsteps = qblk*2 + 2;            // KV tiles of 64 keys
    for (int i = 0; i < nsteps; ++i) {
      const int k0 = i*64;
      store_tile(i & 1);
      __syncthreads();
      if (i + 1 < nsteps)      load_tile(k0 + 64);  // prefetch overlaps compute
      else if (item == 0)      load_tile(0);        // prefetch item 2's tile 0
      if (k0 <= qw + 31) {                          // wave-uniform causal skip
        const bf16* kb = smem + (i & 1)*BUFELEMS;
        const bf16* vb = kb + KELEMS;

        // ---- S^T = K_tile * Q^T: 4 key-subtiles x 2 q-subtiles ----
        f32x4 sacc[4][2];
#pragma unroll
        for (int mt = 0; mt < 4; ++mt)
#pragma unroll
          for (int nt = 0; nt < 2; ++nt)
            sacc[mt][nt] = (f32x4){0.f, 0.f, 0.f, 0.f};
#pragma unroll
        for (int c = 0; c < 4; ++c)
#pragma unroll
          for (int mt = 0; mt < 4; ++mt) {
            const u32x4 af = *(const u32x4*)(kb + mt*16*DH + l15*DH + sw_qk[c]);
            sacc[mt][0] = __builtin_amdgcn_mfma_f32_16x16x32_bf16(
                __builtin_bit_cast(s16x8, af), __builtin_bit_cast(s16x8, qf[0][c]),
                sacc[mt][0], 0, 0, 0);
            sacc[mt][1] = __builtin_amdgcn_mfma_f32_16x16x32_bf16(
                __builtin_bit_cast(s16x8, af), __builtin_bit_cast(s16x8, qf[1][c]),
                sacc[mt][1], 0, 0, 0);
          }

        // ---- online softmax in exp2 space (mask only near diagonal) ----
        const bool needmask = (k0 + 63 > qw);     // wave-uniform
        float alpha[2];
        s16x4 pa[4][2];
#pragma unroll
        for (int nt = 0; nt < 2; ++nt) {
          const int qgl = qw + nt*16 + l15;
          float tmax = -3e38f;
#pragma unroll
          for (int mt = 0; mt < 4; ++mt)
#pragma unroll
            for (int r = 0; r < 4; ++r) {
              float sv = sacc[mt][nt][r];
              if (needmask) {
                const int key = k0 + mt*16 + quad*4 + r;
                sv = (key <= qgl) ? sv : -3e38f;
              }
              sacc[mt][nt][r] = sv;
              tmax = fmaxf(tmax, sv);
            }
          tmax = fmaxf(tmax, __shfl_xor(tmax, 16));
          tmax = fmaxf(tmax, __shfl_xor(tmax, 32));
          const float mnew = fmaxf(m_run[nt], tmax);
          alpha[nt] = __builtin_amdgcn_exp2f(m_run[nt] - mnew);
          m_run[nt] = mnew;
          float rsum = 0.f;
#pragma unroll
          for (int mt = 0; mt < 4; ++mt)
#pragma unroll
            for (int r = 0; r < 4; ++r) {
              const float e = __builtin_amdgcn_exp2f(sacc[mt][nt][r] - mnew);
              sacc[mt][nt][r] = e;
              rsum += e;
            }
          rsum += __shfl_xor(rsum, 16);
          rsum += __shfl_xor(rsum, 32);
          l_run[nt] = l_run[nt]*alpha[nt] + rsum;
#pragma unroll
          for (int mt = 0; mt < 4; ++mt) {   // pack P (already in A-layout)
            union { bf16 hh[4]; s16x4 s; } u;
#pragma unroll
            for (int r = 0; r < 4; ++r) u.hh[r] = (bf16)sacc[mt][nt][r];
            pa[mt][nt] = u.s;
          }
        }

        // ---- rescale O by alpha of its own rows ----
#pragma unroll
        for (int MT = 0; MT < 2; ++MT)
#pragma unroll
          for (int r = 0; r < 4; ++r) {
            const float a = __shfl(alpha[MT], (lane & 48) | (quad*4 + r));
#pragma unroll
            for (int nd = 0; nd < 8; ++nd) oacc[MT][nd][r] *= a;
          }

        // ---- O += P * V ----
#pragma unroll
        for (int kt = 0; kt < 4; ++kt)
#pragma unroll
          for (int nd = 0; nd < 8; ++nd) {
            const s16x4 bv = *(const s16x4*)(vb + nd*16*KTILE + l15*KTILE + sw_pv[kt]);
            oacc[0][nd] = __builtin_amdgcn_mfma_f32_16x16x16bf16_1k(
                pa[kt][0], bv, oacc[0][nd], 0, 0, 0);
            oacc[1][nd] = __builtin_amdgcn_mfma_f32_16x16x16bf16_1k(
                pa[kt][1], bv, oacc[1][nd], 0, 0, 0);
          }
      }
    }

    // ---- epilogue: O / l, fp32 store ----
#pragma unroll
    for (int MT = 0; MT < 2; ++MT)
#pragma unroll
      for (int r = 0; r < 4; ++r) {
        const float li  = __shfl(l_run[MT], (lane & 48) | (quad*4 + r));
        const float inv = 1.0f / li;
        const size_t base = (size_t)(b*S_LEN + qw + MT*16 + quad*4 + r)*QSTRIDE
                          + h*DH + l15;
#pragma unroll
        for (int nd = 0; nd < 8; ++nd)
          og[base + nd*16] = oacc[MT][nd][r] * inv;
      }
  }
}

extern "C" void kernel_launch(void* const* d_in, const int* in_sizes, int n_in,
                              void* d_out, int out_size, void* d_ws, size_t ws_size,
                              hipStream_t stream) {
  const float* q = (const float*)d_in[0];
  const float* k = (const float*)d_in[1];
  const float* v = (const float*)d_in[2];
  float* out = (float*)d_out;
  dim3 grid(8, HQ, 2);    // 8 balanced q-tile pairs x 32 heads x 2 batches
  dim3 block(256);
  attn_fwd<<<grid, block, 0, stream>>>(q, k, v, out);
}

// Round 3
// 233.873 us; speedup vs baseline: 1.7148x; 1.7148x over previous
//
#include <hip/hip_runtime.h>
#include <stdint.h>
#include <stddef.h>

// Causal GQA prefill attention, MI355X gfx950.
// Round 3: 8-wave blocks (16 waves/CU), K/V pre-packed to bf16 tile images in
// d_ws by a memory-bound pre-pass, main-loop staging via global_load_lds DMA
// (zero staging VALU), double-buffered 2x32KB LDS, one barrier per 64-key step.
//
// Verified orientation trick (rounds 0-2): S^T = K*Q^T via mfma_16x16x32_bf16;
// its C-layout (row=key=quad*4+r, col=q=l15) equals the A-operand layout of
// mfma_16x16x16bf16_1k, so softmaxed P feeds PV straight from registers.
//
// Tile image layout (32768 B per 64-key tile, contiguous; LDS image identical):
//   K-part  (16384 B): chunk c in 0..15, key r in 0..63:
//       bytes [c*1024 + r*16] = K[r][c*8 .. c*8+7] (bf16x8)
//   V-part  (16384 B): unit u in 0..15, d in 0..127:
//       bytes [16384 + u*1024 + d*8] = V[u*4 .. u*4+3][d] (V^T, bf16x4)
// Both have row strides of 16/8 B inside 1KB blocks -> QK b128 reads and PV
// b64 reads are <=2-way per quarter-wave (free per m136).

#define S_LEN   2048
#define HQ      32
#define HKV     8
#define DH      128
#define QSTRIDE (HQ*DH)
#define KSTRIDE (HKV*DH)
// (1/sqrt(128)) * log2(e): softmax in exp2 space
#define SCALE_L2 0.12751139830213113f

#define KTILE      64
#define NTILES     (S_LEN/KTILE)          // 32
#define TILE_ELEMS 16384                  // bf16 elems per tile image (32 KB)
#define KPART      8192                   // elems in K-part

typedef __bf16 bf16;
typedef short        s16x4 __attribute__((ext_vector_type(4)));
typedef short        s16x8 __attribute__((ext_vector_type(8)));
typedef float        f32x4 __attribute__((ext_vector_type(4)));
typedef unsigned int u32x2 __attribute__((ext_vector_type(2)));
typedef unsigned int u32x4 __attribute__((ext_vector_type(4)));

__device__ __forceinline__ unsigned int pk2(float a, float b) {
  union { bf16 h[2]; unsigned int u; } x;
  x.h[0] = (bf16)a; x.h[1] = (bf16)b;    // fptrunc = RNE
  return x.u;
}

__device__ __forceinline__ void dma16(const void* g, void* l) {
  // 16B/lane direct global->LDS; LDS dest = uniform base + lane*16 (m97/m104)
  __builtin_amdgcn_global_load_lds(
      (const __attribute__((address_space(1))) unsigned int*)g,
      (__attribute__((address_space(3))) unsigned int*)l, 16, 0, 0);
}

// ---------------- pre-pass: fp32 K/V -> bf16 swizzled tile images ----------
__global__ __launch_bounds__(256)
void prepack(const float* __restrict__ kg, const float* __restrict__ vg,
             bf16* __restrict__ ws) {
  const int t   = blockIdx.x;            // tile 0..31
  const int hkv = blockIdx.y;
  const int b   = blockIdx.z;
  const int tid = threadIdx.x;
  bf16* img = ws + (size_t)((b*HKV + hkv)*NTILES + t)*TILE_ELEMS;

  // K-part: thread handles row key=tid>>2, d-cols (tid&3)*32..+31
  {
    const int key = tid >> 2, cg = tid & 3;
    const float* kp = kg + (size_t)(b*S_LEN + t*KTILE + key)*KSTRIDE
                         + hkv*DH + cg*32;
    float4 x[8];
#pragma unroll
    for (int i = 0; i < 8; ++i) x[i] = ((const float4*)kp)[i];
#pragma unroll
    for (int ii = 0; ii < 4; ++ii) {
      const int chunk = cg*4 + ii;
      u32x4 w;
      w[0] = pk2(x[2*ii].x,   x[2*ii].y);   w[1] = pk2(x[2*ii].z,   x[2*ii].w);
      w[2] = pk2(x[2*ii+1].x, x[2*ii+1].y); w[3] = pk2(x[2*ii+1].z, x[2*ii+1].w);
      *(u32x4*)(img + chunk*512 + key*8) = w;
    }
  }
  // V-part: thread handles keys 2vj,2vj+1, d-range dg*16..+15
  {
    const int vj = tid & 31, dg = tid >> 5;
    const float* v0 = vg + (size_t)(b*S_LEN + t*KTILE + 2*vj)*KSTRIDE
                         + hkv*DH + dg*16;
    const float* v1 = v0 + KSTRIDE;
    float4 a[4], c[4];
#pragma unroll
    for (int i = 0; i < 4; ++i) { a[i] = ((const float4*)v0)[i];
                                  c[i] = ((const float4*)v1)[i]; }
    const float* f0 = (const float*)a;
    const float* f1 = (const float*)c;
    bf16* vimg = img + KPART;
    const int unit = vj >> 1, slot = (vj & 1)*2;
#pragma unroll
    for (int i = 0; i < 16; ++i) {
      const int d = dg*16 + i;
      *(unsigned int*)(vimg + unit*512 + d*4 + slot) = pk2(f0[i], f1[i]);
    }
  }
}

// ---------------- main kernel ----------------------------------------------
template<bool USE_WS>
__global__ __launch_bounds__(512, 4)
void attn_fwd(const float* __restrict__ qg, const float* __restrict__ kg,
              const float* __restrict__ vg, float* __restrict__ og,
              const bf16* __restrict__ ws) {
  __shared__ bf16 smem[2*TILE_ELEMS];    // 65,536 B, double-buffered

  const int tid   = threadIdx.x;
  const int lane  = tid & 63;
  const int wave  = tid >> 6;            // 8 waves/block
  const int l15   = lane & 15;
  const int quad  = lane >> 4;
  const int pairp = blockIdx.x;          // 0..7
  const int h     = blockIdx.y;          // 0..31
  const int b     = blockIdx.z;          // 0..1
  const int hkv   = h >> 2;

  const bf16* imgs = USE_WS ? ws + (size_t)(b*HKV + hkv)*NTILES*TILE_ELEMS
                            : nullptr;

  // fallback staging roles (USE_WS=false): 512 threads
  const int fk_key = tid >> 3, fk_cg = tid & 7;      // K: 2 chunks / thread
  const int fv_u   = tid & 15, fv_dq = tid >> 4;     // V: unit, d-quad
  float4 fkx[4], fvx[4];

  auto load_regs = [&](int t) {
    const float* kp = kg + (size_t)(b*S_LEN + t*KTILE + fk_key)*KSTRIDE
                         + hkv*DH + fk_cg*16;
#pragma unroll
    for (int i = 0; i < 4; ++i) fkx[i] = ((const float4*)kp)[i];
    const int d0 = fv_dq*4;
#pragma unroll
    for (int j = 0; j < 4; ++j)
      fvx[j] = *(const float4*)(vg + (size_t)(b*S_LEN + t*KTILE + fv_u*4 + j)*KSTRIDE
                                   + hkv*DH + d0);
  };
  auto store_tile = [&](int bi) {
    bf16* kb = smem + bi*TILE_ELEMS;
#pragma unroll
    for (int ii = 0; ii < 2; ++ii) {
      u32x4 w;
      w[0] = pk2(fkx[2*ii].x,   fkx[2*ii].y);   w[1] = pk2(fkx[2*ii].z,   fkx[2*ii].w);
      w[2] = pk2(fkx[2*ii+1].x, fkx[2*ii+1].y); w[3] = pk2(fkx[2*ii+1].z, fkx[2*ii+1].w);
      *(u32x4*)(kb + (fk_cg*2 + ii)*512 + fk_key*8) = w;
    }
    bf16* vb = kb + KPART;
    const float* g0 = (const float*)&fvx[0];
    const float* g1 = (const float*)&fvx[1];
    const float* g2 = (const float*)&fvx[2];
    const float* g3 = (const float*)&fvx[3];
#pragma unroll
    for (int i = 0; i < 4; ++i) {
      u32x2 w;
      w[0] = pk2(g0[i], g1[i]);
      w[1] = pk2(g2[i], g3[i]);
      *(u32x2*)(vb + fv_u*512 + (fv_dq*4 + i)*4) = w;
    }
  };

  auto dma_tile = [&](int t, int bi) {     // USE_WS: 4 x 1KB chunks per wave
    const bf16* timg = imgs + (size_t)t*TILE_ELEMS;
    bf16* lbase = smem + bi*TILE_ELEMS;
#pragma unroll
    for (int j = 0; j < 4; ++j) {
      const int off = (wave*4 + j)*512;
      dma16(timg + off + lane*8, lbase + off);
    }
  };

  f32x4 oacc[8];
  float m_run, l_run;
  u32x4 qf[4];

  const int qbs[2] = { pairp, 15 - pairp };     // balanced: 34 steps total
  if (USE_WS) dma_tile(0, 0); else load_regs(0);

  int gs = 0;                                   // flat step counter
#pragma unroll 1
  for (int item = 0; item < 2; ++item) {
    const int qblk = qbs[item];
    const int qw   = qblk*128 + wave*16;        // this wave's 16 q-rows
    const int nst  = qblk*2 + 2;

    // Q fragments (B-operand of S^T = K*Q^T), scale*log2e folded in
    {
      const float* qp = qg + (size_t)(b*S_LEN + qw + l15)*QSTRIDE
                           + h*DH + quad*8;
#pragma unroll
      for (int c = 0; c < 4; ++c) {
        const float4 a4 = ((const float4*)(qp + c*32))[0];
        const float4 b4 = ((const float4*)(qp + c*32))[1];
        u32x4 w;
        w[0] = pk2(a4.x*SCALE_L2, a4.y*SCALE_L2);
        w[1] = pk2(a4.z*SCALE_L2, a4.w*SCALE_L2);
        w[2] = pk2(b4.x*SCALE_L2, b4.y*SCALE_L2);
        w[3] = pk2(b4.z*SCALE_L2, b4.w*SCALE_L2);
        qf[c] = w;
      }
    }
#pragma unroll
    for (int nd = 0; nd < 8; ++nd) oacc[nd] = (f32x4){0.f, 0.f, 0.f, 0.f};
    m_run = -3e38f; l_run = 0.f;

#pragma unroll 1
    for (int i = 0; i < nst; ++i, ++gs) {
      const int k0  = i*KTILE;
      const int buf = gs & 1;
      if (!USE_WS) store_tile(buf);            // waits vmcnt on prefetch regs
      __syncthreads();                         // tile `gs` visible in buf
      // prefetch next step's tile into the other buffer
      const bool more  = (i + 1 < nst);
      const bool cross = (!more) && (item == 0);
      if (USE_WS) {
        if (more)       dma_tile(i + 1, buf ^ 1);
        else if (cross) dma_tile(0,     buf ^ 1);
      } else {
        if (more)       load_regs(i + 1);
        else if (cross) load_regs(0);
      }

      if (k0 <= qw + 15) {                     // wave-uniform causal skip
        const bf16* kb = smem + buf*TILE_ELEMS;
        const bf16* vb = kb + KPART;

        // ---- S^T = K_tile * Q^T : 4 key-subtiles ----
        f32x4 sacc[4];
#pragma unroll
        for (int mt = 0; mt < 4; ++mt) sacc[mt] = (f32x4){0.f, 0.f, 0.f, 0.f};
#pragma unroll
        for (int c = 0; c < 4; ++c) {
#pragma unroll
          for (int mt = 0; mt < 4; ++mt) {
            const u32x4 af = *(const u32x4*)(kb + (c*4 + quad)*512
                                                + (mt*16 + l15)*8);
            sacc[mt] = __builtin_amdgcn_mfma_f32_16x16x32_bf16(
                __builtin_bit_cast(s16x8, af), __builtin_bit_cast(s16x8, qf[c]),
                sacc[mt], 0, 0, 0);
          }
        }

        // ---- online softmax in exp2 space (per-lane state: q = qw + l15) --
        const bool needmask = (k0 + KTILE - 1 > qw);   // wave-uniform
        const int  qgl = qw + l15;
        float tmax = -3e38f;
#pragma unroll
        for (int mt = 0; mt < 4; ++mt)
#pragma unroll
          for (int r = 0; r < 4; ++r) {
            float sv = sacc[mt][r];
            if (needmask) {
              const int key = k0 + mt*16 + quad*4 + r;
              sv = (key <= qgl) ? sv : -3e38f;
            }
            sacc[mt][r] = sv;
            tmax = fmaxf(tmax, sv);
          }
        tmax = fmaxf(tmax, __shfl_xor(tmax, 16));
        tmax = fmaxf(tmax, __shfl_xor(tmax, 32));
        const float mnew  = fmaxf(m_run, tmax);
        const float alpha = __builtin_amdgcn_exp2f(m_run - mnew);
        m_run = mnew;
        float rsum = 0.f;
#pragma unroll
        for (int mt = 0; mt < 4; ++mt)
#pragma unroll
          for (int r = 0; r < 4; ++r) {
            const float e = __builtin_amdgcn_exp2f(sacc[mt][r] - mnew);
            sacc[mt][r] = e;
            rsum += e;
          }
        rsum += __shfl_xor(rsum, 16);
        rsum += __shfl_xor(rsum, 32);
        l_run = l_run*alpha + rsum;

        s16x4 pa[4];
#pragma unroll
        for (int mt = 0; mt < 4; ++mt) {       // P already in A-layout
          union { bf16 hh[4]; s16x4 s; } u;
#pragma unroll
          for (int r = 0; r < 4; ++r) u.hh[r] = (bf16)sacc[mt][r];
          pa[mt] = u.s;
        }

        // ---- rescale O rows (row = quad*4 + r) ----
#pragma unroll
        for (int r = 0; r < 4; ++r) {
          const float a = __shfl(alpha, (lane & 48) | (quad*4 + r));
#pragma unroll
          for (int nd = 0; nd < 8; ++nd) oacc[nd][r] *= a;
        }

        // ---- O += P * V ----
#pragma unroll
        for (int kt = 0; kt < 4; ++kt)
#pragma unroll
          for (int nd = 0; nd < 8; ++nd) {
            const s16x4 bv = *(const s16x4*)(vb + (kt*4 + quad)*512
                                                + (nd*16 + l15)*4);
            oacc[nd] = __builtin_amdgcn_mfma_f32_16x16x16bf16_1k(
                pa[kt], bv, oacc[nd], 0, 0, 0);
          }
      }
    }

    // ---- epilogue: O / l, fp32 store ----
#pragma unroll
    for (int r = 0; r < 4; ++r) {
      const float li  = __shfl(l_run, (lane & 48) | (quad*4 + r));
      const float inv = 1.0f / li;
      const size_t base = (size_t)(b*S_LEN + qw + quad*4 + r)*QSTRIDE
                        + h*DH + l15;
#pragma unroll
      for (int nd = 0; nd < 8; ++nd)
        og[base + nd*16] = oacc[nd][r] * inv;
    }
  }
}

extern "C" void kernel_launch(void* const* d_in, const int* in_sizes, int n_in,
                              void* d_out, int out_size, void* d_ws, size_t ws_size,
                              hipStream_t stream) {
  const float* q = (const float*)d_in[0];
  const float* k = (const float*)d_in[1];
  const float* v = (const float*)d_in[2];
  float* out = (float*)d_out;
  const size_t need = (size_t)2*HKV*NTILES*TILE_ELEMS*sizeof(bf16); // 16.78 MB
  dim3 grid(8, HQ, 2);       // 8 balanced pairs x 32 heads x 2 batches
  dim3 block(512);
  if (ws_size >= need) {
    bf16* ws = (bf16*)d_ws;
    prepack<<<dim3(NTILES, HKV, 2), 256, 0, stream>>>(k, v, ws);
    attn_fwd<true><<<grid, block, 0, stream>>>(q, k, v, out, ws);
  } else {
    attn_fwd<false><<<grid, block, 0, stream>>>(q, k, v, out, nullptr);
  }
}